// Round 6
// baseline (377.637 us; speedup 1.0000x reference)
//
#include <hip/hip_runtime.h>

// RouteNet f32. stats -> prep -> bias/bfold -> k_gemm3 -> k_act(+bank0 stats)
// -> k_banks (fused, 15 stages, atomic-flag barriers) -> k_out.
// R7: k_out 64x128 tile. R8/9: gemm3 dbuf regressed (VGPR) -> reverted.
// R10: fused k_banks 178us. R11: barrier diet (4 slots, in-place norm, early-edge
//   hoist, 256blk) -> 116us = 6.6us/barrier; flag = 256 same-address RMWs.
// R12 (this):
//   k_banks: 8 sub-flags/stage (32 adds per address) + lane-parallel poll;
//            8 stats slots (was 4) -> half write contention; read 2 loads/thread.
//   k_gemm3: 32-row tiles, K-split 6 -> grid (256,6)=1536 blocks=6/CU (was 2/CU);
//            occupancy was the limiter (41% VALU, 10.8% HBM, latency-bound).

#define BATCH 8192
#define NIN 3072
#define DD 32
#define NB 16
#define NOUT 1000
#define TGOFF (BATCH * NOUT)
#define BNEPS 1e-5f
#define NBLK 256
#define ROWS 32
#define NSLOT 8

// ws float offsets
#define O_SUM 0          // [3072] (dead after k_prep; first 128 ints reused as flags)
#define O_FLAG 0         // [16][8] int sub-flags, re-zeroed by memset after k_prep
#define O_SUM2 3072      // [3072]
#define O_STATS2 6144    // [16 banks][8 slots][64] sum/sumsq (8192 floats)
#define O_TG 22528       // [8192]
#define ZERO_FLOATS 30720
#define O_SCALE 30720    // [3072]
#define O_SHIFT 33792    // [3072]
#define O_BIAS 36864     // [64]
#define O_BP 36928       // [3072][64] folded B'
#define O_ACTS 233536    // [16][8192][32] raw acts (banks 0,1,14,15 used)
#define O_ACC (O_ACTS + 2 * BATCH * DD)   // [6][8192][64] gemm partials (banks 2..13.x)

// ---- K1: column stats of x ----
__global__ void __launch_bounds__(256) k_stats(const float* __restrict__ x, float* __restrict__ ws) {
    int c = blockIdx.x * 256 + threadIdx.x;
    const float* p = x + (size_t)blockIdx.y * 128 * NIN + c;
    float s = 0.f, s2 = 0.f;
#pragma unroll 8
    for (int i = 0; i < 128; i++) { float v = p[(size_t)i * NIN]; s += v; s2 += v * v; }
    atomicAdd(&ws[O_SUM + c], s);
    atomicAdd(&ws[O_SUM2 + c], s2);
}

// ---- K2: scale/shift; seed fused bias with b_in ----
__global__ void __launch_bounds__(256) k_prep(float* __restrict__ ws, const float* __restrict__ g,
                                              const float* __restrict__ b, const float* __restrict__ b_in) {
    int c = blockIdx.x * 256 + threadIdx.x;
    float mean = ws[O_SUM + c] * (1.f / BATCH);
    float var = ws[O_SUM2 + c] * (1.f / BATCH) - mean * mean;
    float sc = g[c] * rsqrtf(fmaxf(var, 0.f) + BNEPS);
    ws[O_SCALE + c] = sc;
    ws[O_SHIFT + c] = b[c] - mean * sc;
    if (c < 64) ws[O_BIAS + c] = b_in[c];
}

// ---- K3a: bias' += shift @ W_in ----
__global__ void __launch_bounds__(256) k_bias(float* __restrict__ ws, const float* __restrict__ W_in) {
    int bank = blockIdx.x & 1, jc = blockIdx.x >> 1;
    int d = threadIdx.x & 31, js = threadIdx.x >> 5;
    int j0 = jc * 256 + js * 32;
    float a = 0.f;
    for (int j = 0; j < 32; j++)
        a += ws[O_SHIFT + j0 + j] * W_in[(size_t)bank * NIN * DD + (size_t)(j0 + j) * DD + d];
    __shared__ float red[8][32];
    red[js][d] = a;
    __syncthreads();
    if (threadIdx.x < 32) {
        float t = 0.f;
#pragma unroll
        for (int g8 = 0; g8 < 8; g8++) t += red[g8][threadIdx.x];
        atomicAdd(&ws[O_BIAS + bank * 32 + threadIdx.x], t);
    }
}

// ---- K3b: B'[j][c] = scale[j] * W_in[c>>5][j][c&31] ----
__global__ void __launch_bounds__(256) k_bfold(float* __restrict__ ws, const float* __restrict__ W_in) {
    int idx = blockIdx.x * 256 + threadIdx.x;
    int j = idx >> 6, c = idx & 63;
    ws[O_BP + idx] = ws[O_SCALE + j] * W_in[(size_t)(c >> 5) * NIN * DD + (size_t)j * DD + (c & 31)];
}

// ---- K4: input GEMM. grid (256,6): 32 rows x 64 cols per block, K-split 6 (512 each).
// 1536 blocks = 6/CU = 6 waves/SIMD (occupancy was the limiter at grid 512). ----
__global__ void __launch_bounds__(256) k_gemm3(const float* __restrict__ x, float* __restrict__ ws) {
    __shared__ float xL[32][20];   // 16 k + pad4
    __shared__ float bL[16][64];
    int tid = threadIdx.x;
    int row0 = blockIdx.x * 32;
    int k00 = blockIdx.y * 512;
    const float* bp = ws + O_BP;
    float acc[2][4] = {};
    int tx = tid & 15, rt = tid >> 4;      // cols tx*4, rows rt*2
    int lr = tid >> 3, lq = tid & 7;       // x loader: float2
    int br = tid >> 4, bq = tid & 15;      // b loader: float4
    for (int kc = 0; kc < 32; kc++) {
        int k0 = k00 + kc * 16;
        float2 xv = *(const float2*)&x[(size_t)(row0 + lr) * NIN + k0 + lq * 2];
        float4 bv = *(const float4*)&bp[(size_t)(k0 + br) * 64 + bq * 4];
        __syncthreads();
        *(float2*)&xL[lr][lq * 2] = xv;
        *(float4*)&bL[br][bq * 4] = bv;
        __syncthreads();
#pragma unroll
        for (int kk = 0; kk < 16; kk += 4) {
            float4 b0 = *(float4*)&bL[kk][tx * 4];
            float4 b1 = *(float4*)&bL[kk + 1][tx * 4];
            float4 b2 = *(float4*)&bL[kk + 2][tx * 4];
            float4 b3 = *(float4*)&bL[kk + 3][tx * 4];
#pragma unroll
            for (int j = 0; j < 2; j++) {
                float4 xv4 = *(float4*)&xL[rt * 2 + j][kk];
                acc[j][0] += xv4.x * b0.x + xv4.y * b1.x + xv4.z * b2.x + xv4.w * b3.x;
                acc[j][1] += xv4.x * b0.y + xv4.y * b1.y + xv4.z * b2.y + xv4.w * b3.y;
                acc[j][2] += xv4.x * b0.z + xv4.y * b1.z + xv4.z * b2.z + xv4.w * b3.z;
                acc[j][3] += xv4.x * b0.w + xv4.y * b1.w + xv4.z * b2.w + xv4.w * b3.w;
            }
        }
    }
    float* dst = ws + O_ACC + (size_t)blockIdx.y * (BATCH * 64);
#pragma unroll
    for (int j = 0; j < 2; j++) {
        float4 v = make_float4(acc[j][0], acc[j][1], acc[j][2], acc[j][3]);
        *(float4*)&dst[(size_t)(row0 + rt * 2 + j) * 64 + tx * 4] = v;
    }
}

// ---- K5: reduce 6 K-split partials + bias + relu -> acts banks 0/1; bank-0 stats (8 slots) ----
__global__ void __launch_bounds__(256) k_act(float* __restrict__ ws) {
    __shared__ float sred[16][32];
    __shared__ float qred[16][32];
    int tid = threadIdx.x;
    int i4 = (blockIdx.x * 256 + tid) * 4;
    const float* ac = ws + O_ACC;
    float4 s0 = *(const float4*)&ac[i4];
    float4 s1 = *(const float4*)&ac[524288 + i4];
    float4 s2 = *(const float4*)&ac[1048576 + i4];
    float4 s3 = *(const float4*)&ac[1572864 + i4];
    float4 s4 = *(const float4*)&ac[2097152 + i4];
    float4 s5 = *(const float4*)&ac[2621440 + i4];
    int c = i4 & 63, row = i4 >> 6;
    const float* bias = ws + O_BIAS;
    float4 v;
    v.x = fmaxf(s0.x + s1.x + s2.x + s3.x + s4.x + s5.x + bias[c], 0.f);
    v.y = fmaxf(s0.y + s1.y + s2.y + s3.y + s4.y + s5.y + bias[c + 1], 0.f);
    v.z = fmaxf(s0.z + s1.z + s2.z + s3.z + s4.z + s5.z + bias[c + 2], 0.f);
    v.w = fmaxf(s0.w + s1.w + s2.w + s3.w + s4.w + s5.w + bias[c + 3], 0.f);
    int bank = c >> 5, dd = c & 31;
    *(float4*)&ws[O_ACTS + ((size_t)bank * BATCH + row) * DD + dd] = v;
    int r16 = tid >> 4;
    if (bank == 0) {
        *(float4*)&sred[r16][dd] = v;
        *(float4*)&qred[r16][dd] = make_float4(v.x * v.x, v.y * v.y, v.z * v.z, v.w * v.w);
    }
    __syncthreads();
    if (tid < 32) {
        float sm = 0.f, sq = 0.f;
#pragma unroll
        for (int r = 0; r < 16; r++) { sm += sred[r][tid]; sq += qred[r][tid]; }
        int slot = blockIdx.x & (NSLOT - 1);
        float* st = ws + O_STATS2 + (size_t)slot * 64;   // bank 0
        atomicAdd(&st[tid], sm);
        atomicAdd(&st[32 + tid], sq);
    }
}

// ---- K6: banks t=1..15 fused. 256 blocks x 32 rows (1/CU). Normalized ring;
// early edges pre-barrier; 8 sub-flags + 8 stats slots to cut RMW serialization.
__global__ void __launch_bounds__(256, 2) k_banks(float* __restrict__ ws,
                                                  const float* __restrict__ Wg,
                                                  const float* __restrict__ Wd,
                                                  const float* __restrict__ bd) {
    __shared__ float ring[4][ROWS][32];    // normalized acts, bank s in slot s&3
    __shared__ float WdL[2][4][1024];      // double-buffered edge weights
    __shared__ float sred8[512];           // 8 slots x 64
    __shared__ float m_s[32], iv_s[32];
    __shared__ float red[8][64];
    int tid = threadIdx.x;
    int rg = tid >> 5, d = tid & 31;
    int row0 = blockIdx.x * ROWS;
    int slot8 = blockIdx.x & (NSLOT - 1);
    float* acts = ws + O_ACTS;
    float* stats = ws + O_STATS2;
    int* flag = (int*)(ws + O_FLAG);
    float tg[4] = {0.f, 0.f, 0.f, 0.f};
    float cur[4];
    // prologue: raw bank0 -> ring slot0; bank1 partial -> cur; bank0 stats -> m/iv
#pragma unroll
    for (int ri = 0; ri < 4; ri++) {
        int r = rg + 8 * ri;
        ring[0][r][d] = acts[(size_t)(row0 + r) * DD + d];
        cur[ri] = acts[((size_t)BATCH + row0 + r) * DD + d];
    }
    sred8[tid] = stats[tid];            // kernel boundary: plain loads ok
    sred8[tid + 256] = stats[tid + 256];
    __syncthreads();
    if (tid < 32) {
        float sm = 0.f, sq = 0.f;
#pragma unroll
        for (int s = 0; s < NSLOT; s++) { sm += sred8[s * 64 + tid]; sq += sred8[s * 64 + 32 + tid]; }
        float m = sm * (1.f / BATCH);
        float var = sq * (1.f / BATCH) - m * m;
        m_s[tid] = m;
        iv_s[tid] = rsqrtf(fmaxf(var, 0.f) + BNEPS);
    }
    // prefetch stage-1 Wd (1 edge) into WdL[1]
    ((float4*)&WdL[1][0][0])[tid] = ((const float4*)Wd)[tid];
    __syncthreads();
#pragma unroll
    for (int ri = 0; ri < 4; ri++) {   // normalize bank0 in place
        int r = rg + 8 * ri;
        ring[0][r][d] = (ring[0][r][d] - m_s[d]) * iv_s[d];
    }
    __syncthreads();
    for (int t = 1; t < 16; t++) {
        int buf = t & 1;
        int nE = t < 4 ? t : 4;
        int s0 = t - nE;
        int eb = (t <= 4) ? t * (t - 1) / 2 : 10 + 4 * (t - 5);
        // prefetch next stage's Wd into other buffer
        if (t < 15) {
            int t2 = t + 1;
            int nE2 = t2 < 4 ? t2 : 4;
            int eb2 = (t2 <= 4) ? t2 * (t2 - 1) / 2 : 10 + 4 * (t2 - 5);
            for (int p = tid; p < nE2 * 256; p += 256)
                ((float4*)&WdL[buf ^ 1][0][0])[p] = ((const float4*)(Wd + (size_t)eb2 * 1024))[p];
        }
        float wgr[4], bdr[4];
#pragma unroll
        for (int ei = 0; ei < 4; ei++) {
            wgr[ei] = (ei < nE) ? Wg[(eb + ei) * 32 + d] : 0.f;
            bdr[ei] = (ei < nE) ? bd[(eb + ei) * 32 + d] : 0.f;
        }
        float c_[4];
#pragma unroll
        for (int ri = 0; ri < 4; ri++) c_[ri] = (t == 1) ? cur[ri] : 0.f;
        // EARLY edges (sources <= t-2, already normalized in ring)
#pragma unroll
        for (int ei = 0; ei < 3; ei++) {
            if (ei < nE - 1) {
                int sl = (s0 + ei) & 3;
#pragma unroll
                for (int ri = 0; ri < 4; ri++) {
                    int r = rg + 8 * ri;
                    float g = ring[sl][r][d] * wgr[ei];
                    g += __shfl_xor(g, 1); g += __shfl_xor(g, 2); g += __shfl_xor(g, 4);
                    g += __shfl_xor(g, 8); g += __shfl_xor(g, 16);
                    g = fminf(fmaxf(g, 0.f), 1.f);
                    tg[ri] += g;
                    float dat = bdr[ei];
                    const float* ar = ring[sl][r];
                    const float* wc = &WdL[buf][ei][d];
#pragma unroll
                    for (int k = 0; k < 32; k += 4) {
                        float4 a4 = *(const float4*)&ar[k];
                        dat += a4.x * wc[k * 32] + a4.y * wc[(k + 1) * 32]
                             + a4.z * wc[(k + 2) * 32] + a4.w * wc[(k + 3) * 32];
                    }
                    c_[ri] += g * dat;
                }
            }
        }
        // barrier: wait bank t-1 stats (8 sub-flags, lane-parallel poll)
        if (t > 1) {
            if (tid < 64) {
                int done = 0;
                while (!done) {
                    int f = (tid < NSLOT)
                        ? __hip_atomic_load(&flag[(t - 1) * NSLOT + tid], __ATOMIC_RELAXED, __HIP_MEMORY_SCOPE_AGENT)
                        : 0;
                    f += __shfl_xor(f, 1); f += __shfl_xor(f, 2); f += __shfl_xor(f, 4);
                    done = (__shfl(f, 0) >= NBLK);
                    if (!done) __builtin_amdgcn_s_sleep(2);
                }
            }
            __syncthreads();
            {
                const float* st = stats + (size_t)(t - 1) * NSLOT * 64;
                sred8[tid] = __hip_atomic_load(&st[tid], __ATOMIC_RELAXED, __HIP_MEMORY_SCOPE_AGENT);
                sred8[tid + 256] = __hip_atomic_load(&st[tid + 256], __ATOMIC_RELAXED, __HIP_MEMORY_SCOPE_AGENT);
            }
            __syncthreads();
            if (tid < 32) {
                float sm = 0.f, sq = 0.f;
#pragma unroll
                for (int s = 0; s < NSLOT; s++) { sm += sred8[s * 64 + tid]; sq += sred8[s * 64 + 32 + tid]; }
                float m = sm * (1.f / BATCH);
                float var = sq * (1.f / BATCH) - m * m;
                m_s[tid] = m;
                iv_s[tid] = rsqrtf(fmaxf(var, 0.f) + BNEPS);
            }
            __syncthreads();
            int sl = (t - 1) & 3;
#pragma unroll
            for (int ri = 0; ri < 4; ri++) {
                int r = rg + 8 * ri;
                ring[sl][r][d] = (ring[sl][r][d] - m_s[d]) * iv_s[d];
            }
            __syncthreads();
        }
        // LATE edge (source t-1)
        {
            int ei = nE - 1;
            int sl = (t - 1) & 3;
#pragma unroll
            for (int ri = 0; ri < 4; ri++) {
                int r = rg + 8 * ri;
                float g = ring[sl][r][d] * wgr[ei];
                g += __shfl_xor(g, 1); g += __shfl_xor(g, 2); g += __shfl_xor(g, 4);
                g += __shfl_xor(g, 8); g += __shfl_xor(g, 16);
                g = fminf(fmaxf(g, 0.f), 1.f);
                tg[ri] += g;
                float dat = bdr[ei];
                const float* ar = ring[sl][r];
                const float* wc = &WdL[buf][ei][d];
#pragma unroll
                for (int k = 0; k < 32; k += 4) {
                    float4 a4 = *(const float4*)&ar[k];
                    dat += a4.x * wc[k * 32] + a4.y * wc[(k + 1) * 32]
                         + a4.z * wc[(k + 2) * 32] + a4.w * wc[(k + 3) * 32];
                }
                c_[ri] += g * dat;
            }
        }
        float vv[4];
#pragma unroll
        for (int ri = 0; ri < 4; ri++) vv[ri] = fmaxf(c_[ri], 0.f);
        __syncthreads();   // all ring reads done before slot t&3 overwrite
#pragma unroll
        for (int ri = 0; ri < 4; ri++) {
            int r = rg + 8 * ri;
            ring[t & 3][r][d] = vv[ri];   // raw; normalized at stage t+1
            if (t >= 14) acts[((size_t)t * BATCH + row0 + r) * DD + d] = vv[ri];
        }
        red[rg][d] = vv[0] + vv[1] + vv[2] + vv[3];
        red[rg][32 + d] = vv[0] * vv[0] + vv[1] * vv[1] + vv[2] * vv[2] + vv[3] * vv[3];
        __syncthreads();
        if (tid < 64) {
            float a = 0.f;
#pragma unroll
            for (int g8 = 0; g8 < 8; g8++) a += red[g8][tid];
            atomicAdd(&stats[((size_t)t * NSLOT + slot8) * 64 + tid], a);
        }
        if (t < 15) {
            __syncthreads();           // drains vmcnt: stats atomics at coherent point
            if (tid == 0) atomicAdd(&flag[t * NSLOT + slot8], 1);
        }
    }
    if (d == 0) {
#pragma unroll
        for (int ri = 0; ri < 4; ri++) ws[O_TG + row0 + rg + 8 * ri] = tg[ri];
    }
}

// ---- K7: output GEMM; copy total_gate. 64x128 tile, grid (128,8). ----
__global__ void __launch_bounds__(256) k_out(const float* __restrict__ ws, const float* __restrict__ Wout,
                                             float* __restrict__ out) {
    __shared__ float aLt[32][68];
    __shared__ float wL[32][128];
    __shared__ float mIv[2][2][32];
    int tid = threadIdx.x;
    int row0 = blockIdx.x * 64;
    int col0 = blockIdx.y * 128;
    const float* acts = ws + O_ACTS;
    if (blockIdx.y == 0 && tid < 64) out[TGOFF + row0 + tid] = ws[O_TG + row0 + tid];
    if (tid < 64) {
        int bi = tid >> 5, d = tid & 31;
        const float* st = ws + O_STATS2 + (size_t)(14 + bi) * NSLOT * 64;
        float sm = 0.f, sq = 0.f;
#pragma unroll
        for (int sl = 0; sl < NSLOT; sl++) { sm += st[sl * 64 + d]; sq += st[sl * 64 + 32 + d]; }
        float m = sm * (1.f / BATCH);
        float var = sq * (1.f / BATCH) - m * m;
        mIv[bi][0][d] = m;
        mIv[bi][1][d] = rsqrtf(fmaxf(var, 0.f) + BNEPS);
    }
    int tx = tid & 31, ty = tid >> 5;
    int c4 = col0 + tx * 4;
    bool c4ok = (c4 + 3 < NOUT);
    float acc[8][4] = {};
    for (int bi = 0; bi < 2; bi++) {
        __syncthreads();
        {
            int d = tid & 31, r0 = tid >> 5;
            float m = mIv[bi][0][d], iv = mIv[bi][1][d];
            const float* ap = acts + ((size_t)(14 + bi) * BATCH + row0) * DD + d;
#pragma unroll
            for (int i = 0; i < 8; i++) {
                int r = r0 + 8 * i;
                aLt[d][r] = (ap[(size_t)r * DD] - m) * iv;
            }
        }
        {
            const float* wp = Wout + (size_t)bi * DD * NOUT + c4;
            int kk0 = tid >> 5;
#pragma unroll
            for (int i = 0; i < 4; i++) {
                int kk = kk0 + 8 * i;
                const float* wr = wp + (size_t)kk * NOUT;
                float4 v;
                if (c4ok) {
                    v = *(const float4*)wr;
                } else {
                    v.x = (c4 + 0 < NOUT) ? wr[0] : 0.f;
                    v.y = (c4 + 1 < NOUT) ? wr[1] : 0.f;
                    v.z = (c4 + 2 < NOUT) ? wr[2] : 0.f;
                    v.w = (c4 + 3 < NOUT) ? wr[3] : 0.f;
                }
                *(float4*)&wL[kk][tx * 4] = v;
            }
        }
        __syncthreads();
#pragma unroll 4
        for (int k = 0; k < 32; k++) {
            float4 w = *(float4*)&wL[k][tx * 4];
            float4 a0 = *(float4*)&aLt[k][ty * 8];
            float4 a1 = *(float4*)&aLt[k][ty * 8 + 4];
            float ar[8] = {a0.x, a0.y, a0.z, a0.w, a1.x, a1.y, a1.z, a1.w};
            float wc[4] = {w.x, w.y, w.z, w.w};
#pragma unroll
            for (int r = 0; r < 8; r++)
#pragma unroll
                for (int c = 0; c < 4; c++)
                    acc[r][c] += ar[r] * wc[c];
        }
    }
    if (c4ok) {
#pragma unroll
        for (int r = 0; r < 8; r++) {
            int row = row0 + ty * 8 + r;
            *(float4*)&out[(size_t)row * NOUT + c4] =
                make_float4(acc[r][0], acc[r][1], acc[r][2], acc[r][3]);
        }
    } else {
#pragma unroll
        for (int r = 0; r < 8; r++) {
            int row = row0 + ty * 8 + r;
#pragma unroll
            for (int c = 0; c < 4; c++)
                if (c4 + c < NOUT) out[(size_t)row * NOUT + c4 + c] = acc[r][c];
        }
    }
}

extern "C" void kernel_launch(void* const* d_in, const int* in_sizes, int n_in,
                              void* d_out, int out_size, void* d_ws, size_t ws_size,
                              hipStream_t stream) {
    (void)in_sizes; (void)n_in; (void)out_size; (void)ws_size;
    const float* x     = (const float*)d_in[0];
    const float* gamma = (const float*)d_in[1];
    const float* beta  = (const float*)d_in[2];
    const float* W_in  = (const float*)d_in[3];
    const float* b_in  = (const float*)d_in[4];
    const float* Wg    = (const float*)d_in[5];
    const float* Wd    = (const float*)d_in[6];
    const float* bd    = (const float*)d_in[7];
    const float* Wout  = (const float*)d_in[8];
    float* out = (float*)d_out;
    float* ws  = (float*)d_ws;

    hipMemsetAsync(d_ws, 0, ZERO_FLOATS * sizeof(float), stream);
    k_stats<<<dim3(12, 64), 256, 0, stream>>>(x, ws);
    k_prep<<<12, 256, 0, stream>>>(ws, gamma, beta, b_in);
    k_bias<<<24, 256, 0, stream>>>(ws, W_in);
    k_bfold<<<768, 256, 0, stream>>>(ws, W_in);
    k_gemm3<<<dim3(256, 6), 256, 0, stream>>>(x, ws);
    k_act<<<512, 256, 0, stream>>>(ws);
    // re-zero barrier flags (O_SUM region dead after k_prep; stream-ordered)
    hipMemsetAsync(ws + O_FLAG, 0, NB * NSLOT * sizeof(int), stream);
    k_banks<<<NBLK, 256, 0, stream>>>(ws, Wg, Wd, bd);
    k_out<<<dim3(128, 8), 256, 0, stream>>>(ws, Wout, out);
}